// Round 11
// baseline (28.450 us; speedup 1.0000x reference)
//
#include <hip/hip_runtime.h>
#include <stdint.h>

// TripletLoss on MI355X. E=8192, N=2048, K=8, L=16, top-400 of Gumbel-perturbed logw.
// Round 11: single 1-block dispatch (validated structure) + three cuts:
//  - 3-pass radix (11/11/10-bit digits), 2048-bin hist reusing dead s_cur region;
//    wave-0 suffix-scan select with 32 bins/lane in-register top-down walk.
//  - probas staged to LDS (dead s_cluA region) during phase C; F's scattered
//    gathers become LDS reads instead of cold L2/HBM.
//  - D's integer div -> v_rcp_f32 + exact fixup (<=1 step).

#define E_CONST 8192
#define N_CONST 2048
#define K_CONST 8
#define L_CONST 16
#define MAXS 400
#define EPS_F 1e-9f
#define NTHR 1024
#define RCAP 4096   // register-resident candidates (4 per thread)
#define TCAP 6144   // pairAnchor table capacity

// ---- dynamic LDS layout (bytes) ----
#define OFF_CLUA   0        // float4[2048] clusters k=0..3  | reused: probas[8192] in C..F
#define OFF_CLUB   32768    // float4[2048] clusters k=4..7
#define OFF_PK     65536    // int[2048]    packed cnt/base: P low16 | N high16
#define OFF_Q      73728    // int[2048]    pair cnt -> pair base
#define OFF_CUR    81920    // int[2048]    packed fill cursors | reused: hist[2048] in E
#define OFF_CSR    90112    // uint16[8192] pos ids [0,nPosTot), neg after
#define OFF_BC     106496   // float[8192]  per-edge Bhattacharyya coeff
#define OFF_CLST   139264   // uint8[2048]  per-node argmax cluster
#define OFF_PA     141312   // uint16[6144] pair -> anchor
#define OFF_TMP    153600   // int[16]
#define OFF_WSUM   153664   // float[16]
#define OFF_WCNT   153728   // int[16]
#define OFF_MISC   153792   // [0]=mask [1]=totPk [2]=totQ [3]=prefix [4]=target
#define LDS_BYTES  153824

struct Cand { float val; uint32_t pack; };

// ---- threefry2x32, key = jax.random.key(42), partitionable path (validated absmax 0.0) ----
__device__ __forceinline__ uint2 threefry2x32_42(uint32_t x0, uint32_t x1) {
    const uint32_t ks0 = 0u, ks1 = 42u;
    const uint32_t ks2 = ks0 ^ ks1 ^ 0x1BD11BDAu;
    const uint32_t ks[3] = {ks0, ks1, ks2};
    const int R[2][4] = {{13, 15, 26, 6}, {17, 29, 16, 24}};
    x0 += ks0; x1 += ks1;
#pragma unroll
    for (int g = 0; g < 5; ++g) {
        const int* r = R[g & 1];
#pragma unroll
        for (int q = 0; q < 4; ++q) {
            x0 += x1;
            x1 = (x1 << r[q]) | (x1 >> (32 - r[q]));
            x1 ^= x0;
        }
        x0 += ks[(g + 1) % 3];
        x1 += ks[(g + 2) % 3] + (uint32_t)(g + 1);
    }
    return make_uint2(x0, x1);
}

__device__ __forceinline__ float gumbel_at(uint32_t idx) {
    uint2 o = threefry2x32_42(0u, idx);
    uint32_t bits = o.x ^ o.y;
    float u = __uint_as_float((bits >> 9) | 0x3F800000u) - 1.0f;
    return -__logf(-__logf(u + EPS_F) + EPS_F);  // ranking-only: native log ok
}

__device__ __forceinline__ uint32_t sortable_key(float f) {
    uint32_t b = __float_as_uint(f);
    return (b & 0x80000000u) ? ~b : (b | 0x80000000u);
}

__device__ __forceinline__ int argmax8(float4 a, float4 b) {
    float v[8] = {a.x, a.y, a.z, a.w, b.x, b.y, b.z, b.w};
    float best = v[0]; int bi = 0;
#pragma unroll
    for (int k = 1; k < 8; ++k)
        if (v[k] > best) { best = v[k]; bi = k; }  // first-max == jnp.argmax
    return bi;
}

// exclusive in-place scan of arr[2048] by 1024 threads (each owns 2 elems).
// Works for 16|16 packed fields: per-field totals < 65536 -> no cross-field carry.
__device__ __forceinline__ void scan_inplace(int* arr, int* tmp, int* totalOut) {
    int tid = threadIdx.x;
    int lane = tid & 63, wid = tid >> 6;
    int i0 = 2 * tid, i1 = i0 + 1;
    int v0 = arr[i0], v1 = arr[i1];
    int s = v0 + v1;
    int inc = s;
#pragma unroll
    for (int off = 1; off < 64; off <<= 1) {
        int u = __shfl_up(inc, off);
        if (lane >= off) inc += u;
    }
    if (lane == 63) tmp[wid] = inc;
    __syncthreads();
    if (wid == 0) {
        int w = (lane < 16) ? tmp[lane] : 0;
        int incw = w;
#pragma unroll
        for (int off = 1; off < 16; off <<= 1) {
            int u = __shfl_up(incw, off);
            if (lane >= off) incw += u;
        }
        if (lane < 16) tmp[lane] = incw - w;  // exclusive wave bases
    }
    __syncthreads();
    int base = tmp[wid] + (inc - s);
    arr[i0] = base;
    arr[i1] = base + v0;
    if (tid == 1023) *totalOut = base + v0 + v1;
    __syncthreads();
}

__global__ __launch_bounds__(1024) void k_all(
    const float* __restrict__ probas, const float* __restrict__ clusters,
    const int* __restrict__ edges, const int* __restrict__ keypts,
    Cand* __restrict__ spill, int pmax, float* __restrict__ out) {

    extern __shared__ char smem[];
    float4*   s_cluA = (float4*)(smem + OFF_CLUA);
    float4*   s_cluB = (float4*)(smem + OFF_CLUB);
    float*    s_prob = (float*)(smem + OFF_CLUA);   // alias: valid after phase C
    int*      s_pk   = (int*)(smem + OFF_PK);
    int*      s_q    = (int*)(smem + OFF_Q);
    int*      s_cur  = (int*)(smem + OFF_CUR);
    int*      s_hist = (int*)(smem + OFF_CUR);      // alias: hist[2048] in phase E
    uint16_t* s_csr  = (uint16_t*)(smem + OFF_CSR);
    float*    s_bc   = (float*)(smem + OFF_BC);
    uint8_t*  s_clst = (uint8_t*)(smem + OFF_CLST);
    uint16_t* s_pa   = (uint16_t*)(smem + OFF_PA);
    int*      s_tmp  = (int*)(smem + OFF_TMP);
    float*    s_wsum = (float*)(smem + OFF_WSUM);
    int*      s_wcnt = (int*)(smem + OFF_WCNT);
    int*      s_misc = (int*)(smem + OFF_MISC);

    int tid = threadIdx.x;

    // preload edges + probas into regs (overlaps cluster-staging latency)
    const int2* ed2 = (const int2*)edges;
    int2 pre[8];
#pragma unroll
    for (int it = 0; it < 8; ++it) pre[it] = ed2[tid + it * NTHR];
    const float4* p4 = (const float4*)probas;
    float4 pp0 = p4[tid], pp1 = p4[tid + 1024];

    s_pk[tid] = 0; s_pk[tid + 1024] = 0;
    if (tid == 0) s_misc[0] = 0;

    // ===== A1: stage clusters coalesced into LDS + per-node argmax =====
    const float4* c4 = (const float4*)clusters;
#pragma unroll
    for (int r = 0; r < 2; ++r) {
        int n = tid + r * 1024;
        float4 a = c4[2 * n], b = c4[2 * n + 1];
        s_cluA[n] = a; s_cluB[n] = b;
        s_clst[n] = (uint8_t)argmax8(a, b);
    }
    __syncthreads();
    if (tid < L_CONST)
        atomicOr((uint32_t*)&s_misc[0], 1u << s_clst[keypts[tid]]);
    __syncthreads();
    uint32_t m = (uint32_t)s_misc[0];

    // ===== A2: per-edge flag + packed counts + precomputed bc (clusters in LDS) =====
    uint32_t af[8];  // anchor(<<2) | flag
#pragma unroll
    for (int it = 0; it < 8; ++it) {
        int e = tid + it * NTHR;
        int2 p = pre[it];
        int c0 = s_clst[p.x], c1 = s_clst[p.y];
        int f = 0;
        if ((((m >> c0) | (m >> c1)) & 1u)) f = (c0 == c1) ? 1 : 2;  // 1=pos, 2=neg
        af[it] = ((uint32_t)p.x << 2) | (uint32_t)f;
        if (f == 1)      atomicAdd(&s_pk[p.x], 1);
        else if (f == 2) atomicAdd(&s_pk[p.x], 0x10000);
        float4 a0 = s_cluA[p.x], a1 = s_cluB[p.x];
        float4 b0 = s_cluA[p.y], b1 = s_cluB[p.y];
        float s = __builtin_amdgcn_sqrtf(a0.x * b0.x);  // k ascending, matches ref order
        s += __builtin_amdgcn_sqrtf(a0.y * b0.y);
        s += __builtin_amdgcn_sqrtf(a0.z * b0.z);
        s += __builtin_amdgcn_sqrtf(a0.w * b0.w);
        s += __builtin_amdgcn_sqrtf(a1.x * b1.x);
        s += __builtin_amdgcn_sqrtf(a1.y * b1.y);
        s += __builtin_amdgcn_sqrtf(a1.z * b1.z);
        s += __builtin_amdgcn_sqrtf(a1.w * b1.w);
        s_bc[e] = s;
    }
    __syncthreads();

    // ===== B: pair counts + in-place scans =====
    {
        int i0 = 2 * tid, i1 = i0 + 1;
        int p0 = s_pk[i0], p1 = s_pk[i1];
        s_q[i0] = (p0 & 0xFFFF) * (p0 >> 16);
        s_q[i1] = (p1 & 0xFFFF) * (p1 >> 16);
    }
    __syncthreads();
    scan_inplace(s_pk, s_tmp, &s_misc[1]);
    scan_inplace(s_q, s_tmp, &s_misc[2]);
    s_cur[2 * tid] = s_pk[2 * tid];
    s_cur[2 * tid + 1] = s_pk[2 * tid + 1];
    __syncthreads();
    int nPosTot = s_misc[1] & 0xFFFF;
    int nNegTot = s_misc[1] >> 16;
    int totQ = s_misc[2];
    int P = totQ; if (P > pmax) P = pmax;

    // ===== C: CSR fill + pairAnchor table + probas->LDS (s_cluA now dead) =====
#pragma unroll
    for (int it = 0; it < 8; ++it) {
        int f = (int)(af[it] & 3u);
        int a = (int)(af[it] >> 2);
        int e = tid + it * NTHR;
        if (f == 1) {
            int old = atomicAdd(&s_cur[a], 1);
            s_csr[old & 0xFFFF] = (uint16_t)e;
        } else if (f == 2) {
            int old = atomicAdd(&s_cur[a], 0x10000);
            s_csr[nPosTot + (old >> 16)] = (uint16_t)e;
        }
    }
    for (int a = tid; a < N_CONST; a += NTHR) {
        int q0 = s_q[a];
        int q1 = (a < N_CONST - 1) ? s_q[a + 1] : totQ;
        for (int t = q0; t < q1 && t < TCAP; ++t) s_pa[t] = (uint16_t)a;
    }
    ((float4*)s_prob)[tid] = pp0;          // overwrite dead cluster region
    ((float4*)s_prob)[tid + 1024] = pp1;
    __syncthreads();

    // ===== D: one thread per valid pair; anchor via table; rcp-based div =====
    auto make_cand = [&](int t, float& val, uint32_t& pack) {
        int a;
        if (t < TCAP) a = (int)s_pa[t];
        else {  // fallback (statistically unused)
            int lo = 0, hi = N_CONST - 1;
#pragma unroll
            for (int itr = 0; itr < 11; ++itr) {
                int mid = (lo + hi + 1) >> 1;
                if (s_q[mid] <= t) lo = mid; else hi = mid - 1;
            }
            a = lo;
        }
        int loc = t - s_q[a];
        int pk = s_pk[a];
        int pb = pk & 0xFFFF, nb = pk >> 16;
        int nextN = (a < N_CONST - 1) ? (s_pk[a + 1] >> 16) : nNegTot;
        int nn = nextN - nb;  // >= 1 for any anchor owning pairs
        int ip = (int)((float)loc * __builtin_amdgcn_rcpf((float)nn));
        while ((ip + 1) * nn <= loc) ++ip;   // exact fixup, <=1 step each
        while (ip * nn > loc) --ip;
        int jn = loc - ip * nn;
        int i = s_csr[pb + ip];
        int j = s_csr[nPosTot + nb + jn];
        float w = 1.0f - 0.5f * (s_bc[i] + s_bc[j]);
        val = (w > 0.0f)
            ? __logf(fmaxf(w, EPS_F)) + gumbel_at((uint32_t)i * E_CONST + (uint32_t)j)
            : -INFINITY;  // ref: logw=-inf -> excluded via ok mask
        pack = ((uint32_t)i << 16) | (uint32_t)j;
    };

    float vval0 = 0.f, vval1 = 0.f, vval2 = 0.f, vval3 = 0.f;  // static-indexed (rule #20)
    uint32_t vpk0 = 0, vpk1 = 0, vpk2 = 0, vpk3 = 0;
    if (tid        < P) make_cand(tid,        vval0, vpk0);
    if (tid + 1024 < P) make_cand(tid + 1024, vval1, vpk1);
    if (tid + 2048 < P) make_cand(tid + 2048, vval2, vpk2);
    if (tid + 3072 < P) make_cand(tid + 3072, vval3, vpk3);
    for (int t = tid + RCAP; t < P; t += NTHR) {  // spill path (statistically unused)
        float v; uint32_t pk;
        make_cand(t, v, pk);
        spill[t - RCAP].val = v; spill[t - RCAP].pack = pk;
    }
    uint32_t vk0 = sortable_key(vval0), vk1 = sortable_key(vval1);
    uint32_t vk2 = sortable_key(vval2), vk3 = sortable_key(vval3);
    __syncthreads();

    // ===== E: 3-pass radix threshold (11/11/10-bit digits, hist[2048] = dead s_cur) =====
    uint32_t* s_prefix = (uint32_t*)&s_misc[3];
    int*      s_target = &s_misc[4];
    int M = P;
    uint32_t thr = 0;
    if (M > MAXS) {
        if (tid == 0) { *s_prefix = 0; *s_target = MAXS; }
        for (int pass = 0; pass < 3; ++pass) {
            const int shift = (pass == 0) ? 21 : (pass == 1) ? 10 : 0;
            const uint32_t dmask = (pass == 2) ? 0x3FFu : 0x7FFu;
            const int csh = (pass == 1) ? 21 : 10;   // bits above digit (pass>0 only)
            const int W = (pass == 2) ? 10 : 11;     // digit width
            s_hist[tid] = 0; s_hist[tid + 1024] = 0;
            __syncthreads();
            uint32_t pfx = *s_prefix;
            auto hist_add = [&](bool inr, uint32_t k) {
                if (!inr) return;
                if (pass != 0 && (k >> csh) != pfx) return;
                atomicAdd(&s_hist[(k >> shift) & dmask], 1);
            };
            hist_add(tid        < M, vk0);
            hist_add(tid + 1024 < M, vk1);
            hist_add(tid + 2048 < M, vk2);
            hist_add(tid + 3072 < M, vk3);
            for (int t = tid + RCAP; t < M; t += NTHR) {
                uint32_t k = sortable_key(spill[t - RCAP].val);
                if (pass == 0 || (k >> csh) == pfx)
                    atomicAdd(&s_hist[(k >> shift) & dmask], 1);
            }
            __syncthreads();
            if (tid < 64) {  // wave 0: lane L owns bins [32L,32L+32); suffix-scan select
                int h[32]; int lsum = 0;
#pragma unroll
                for (int b = 0; b < 32; ++b) { h[b] = s_hist[32 * tid + b]; lsum += h[b]; }
                int sincl = lsum;
#pragma unroll
                for (int off = 1; off < 64; off <<= 1) {
                    int v = __shfl_down(sincl, off);
                    if (tid + off < 64) sincl += v;
                }
                int excl = __shfl_down(sincl, 1);
                if (tid == 63) excl = 0;
                int tgt = *s_target;
                uint32_t pfxOld = *s_prefix;
                if (sincl >= tgt && excl < tgt) {  // exactly one winning lane
                    int acc = excl;
#pragma unroll
                    for (int b = 31; b >= 0; --b) {
                        acc += h[b];
                        if (acc >= tgt) {
                            *s_prefix = (pfxOld << W) | (uint32_t)(32 * tid + b);
                            *s_target = tgt - (acc - h[b]);
                            break;
                        }
                    }
                }
            }
            __syncthreads();
        }
        thr = *s_prefix;  // exact 32-bit sortable key of the 400th-largest value
    }

    // ===== F: deterministic reduce of selected terms (probas from LDS) =====
    float mysum = 0.f;
    int myc = 0;
    auto accum = [&](int t, float v, uint32_t k, uint32_t pk) {
        if (t < M && v != -INFINITY && k >= thr) {
            int i = (int)(pk >> 16), j = (int)(pk & 0xFFFFu);
            float pi = s_prob[i], pj = s_prob[j];
            mysum += __logf(pi / (pi + pj));  // ~1e-6 abs err, threshold 1.7e-2
            myc++;
        }
    };
    accum(tid,        vval0, vk0, vpk0);
    accum(tid + 1024, vval1, vk1, vpk1);
    accum(tid + 2048, vval2, vk2, vpk2);
    accum(tid + 3072, vval3, vk3, vpk3);
    for (int t = tid + RCAP; t < M; t += NTHR) {
        Cand c = spill[t - RCAP];
        accum(t, c.val, sortable_key(c.val), c.pack);
    }
#pragma unroll
    for (int off = 32; off > 0; off >>= 1) {
        mysum += __shfl_down(mysum, off);
        myc   += __shfl_down(myc, off);
    }
    int wid = tid >> 6;
    if ((tid & 63) == 0) { s_wsum[wid] = mysum; s_wcnt[wid] = myc; }
    __syncthreads();
    if (tid == 0) {
        float s = 0.f; int c = 0;
        for (int w = 0; w < 16; ++w) { s += s_wsum[w]; c += s_wcnt[w]; }
        if (c < 1) c = 1;
        out[0] = -s / (float)c;
    }
}

extern "C" void kernel_launch(void* const* d_in, const int* in_sizes, int n_in,
                              void* d_out, int out_size, void* d_ws, size_t ws_size,
                              hipStream_t stream) {
    const float* probas   = (const float*)d_in[0];
    const float* clusters = (const float*)d_in[1];
    const int*   edges    = (const int*)d_in[2];
    const int*   keypts   = (const int*)d_in[3];
    float* out = (float*)d_out;

    Cand* spill = (Cand*)d_ws;
    int spill_cap = (int)(ws_size / sizeof(Cand));
    if (spill_cap > 61440) spill_cap = 61440;
    int pmax = RCAP + spill_cap;

    // allow >64KB dynamic LDS (idempotent host-side call; not a stream op)
    hipFuncSetAttribute((const void*)k_all,
                        hipFuncAttributeMaxDynamicSharedMemorySize, LDS_BYTES);

    k_all<<<1, NTHR, LDS_BYTES, stream>>>(probas, clusters, edges, keypts,
                                          spill, pmax, out);
}

// Round 12
// 26.174 us; speedup vs baseline: 1.0870x; 1.0870x over previous
//
#include <hip/hip_runtime.h>
#include <stdint.h>

// TripletLoss on MI355X. E=8192, N=2048, K=8, L=16, top-400 of Gumbel-perturbed logw.
// Round 12: R10 verbatim (best-known, 26.2us) + ONE isolated change: probas staged
// to LDS (dead s_cluA region, written in phase C) so phase F's ~1600 scattered 4B
// reads hit LDS instead of cold HBM (L2/L3 wiped by harness poison fills).
// R11's other pieces (2048-bin radix, rcp div) reverted — they regressed.

#define E_CONST 8192
#define N_CONST 2048
#define K_CONST 8
#define L_CONST 16
#define MAXS 400
#define EPS_F 1e-9f
#define NTHR 1024
#define RCAP 4096   // register-resident candidates (4 per thread)
#define TCAP 6144   // pairAnchor table capacity

// ---- dynamic LDS layout (bytes) ----
#define OFF_CLUA   0        // float4[2048] clusters k=0..3 | reused: probas[8192] from C
#define OFF_CLUB   32768    // float4[2048] clusters k=4..7
#define OFF_PK     65536    // int[2048]    packed cnt/base: P low16 | N high16
#define OFF_Q      73728    // int[2048]    pair cnt -> pair base
#define OFF_CUR    81920    // int[2048]    packed fill cursors
#define OFF_CSR    90112    // uint16[8192] pos ids [0,nPosTot), neg after
#define OFF_BC     106496   // float[8192]  per-edge Bhattacharyya coeff
#define OFF_CLST   139264   // uint8[2048]  per-node argmax cluster
#define OFF_PA     141312   // uint16[6144] pair -> anchor
#define OFF_TMP    153600   // int[16]
#define OFF_HIST   153664   // int[256]
#define OFF_WSUM   154688   // float[16]
#define OFF_WCNT   154752   // int[16]
#define OFF_MISC   154816   // [0]=mask [1]=totPk [2]=totQ [3]=prefix [4]=target
#define LDS_BYTES  154848

struct Cand { float val; uint32_t pack; };

// ---- threefry2x32, key = jax.random.key(42), partitionable path (validated absmax 0.0) ----
__device__ __forceinline__ uint2 threefry2x32_42(uint32_t x0, uint32_t x1) {
    const uint32_t ks0 = 0u, ks1 = 42u;
    const uint32_t ks2 = ks0 ^ ks1 ^ 0x1BD11BDAu;
    const uint32_t ks[3] = {ks0, ks1, ks2};
    const int R[2][4] = {{13, 15, 26, 6}, {17, 29, 16, 24}};
    x0 += ks0; x1 += ks1;
#pragma unroll
    for (int g = 0; g < 5; ++g) {
        const int* r = R[g & 1];
#pragma unroll
        for (int q = 0; q < 4; ++q) {
            x0 += x1;
            x1 = (x1 << r[q]) | (x1 >> (32 - r[q]));
            x1 ^= x0;
        }
        x0 += ks[(g + 1) % 3];
        x1 += ks[(g + 2) % 3] + (uint32_t)(g + 1);
    }
    return make_uint2(x0, x1);
}

__device__ __forceinline__ float gumbel_at(uint32_t idx) {
    uint2 o = threefry2x32_42(0u, idx);
    uint32_t bits = o.x ^ o.y;
    float u = __uint_as_float((bits >> 9) | 0x3F800000u) - 1.0f;
    return -__logf(-__logf(u + EPS_F) + EPS_F);  // ranking-only: native log ok
}

__device__ __forceinline__ uint32_t sortable_key(float f) {
    uint32_t b = __float_as_uint(f);
    return (b & 0x80000000u) ? ~b : (b | 0x80000000u);
}

__device__ __forceinline__ int argmax8(float4 a, float4 b) {
    float v[8] = {a.x, a.y, a.z, a.w, b.x, b.y, b.z, b.w};
    float best = v[0]; int bi = 0;
#pragma unroll
    for (int k = 1; k < 8; ++k)
        if (v[k] > best) { best = v[k]; bi = k; }  // first-max == jnp.argmax
    return bi;
}

// exclusive in-place scan of arr[2048] by 1024 threads (each owns 2 elems).
// Works for 16|16 packed fields: per-field totals < 65536 -> no cross-field carry.
__device__ __forceinline__ void scan_inplace(int* arr, int* tmp, int* totalOut) {
    int tid = threadIdx.x;
    int lane = tid & 63, wid = tid >> 6;
    int i0 = 2 * tid, i1 = i0 + 1;
    int v0 = arr[i0], v1 = arr[i1];
    int s = v0 + v1;
    int inc = s;
#pragma unroll
    for (int off = 1; off < 64; off <<= 1) {
        int u = __shfl_up(inc, off);
        if (lane >= off) inc += u;
    }
    if (lane == 63) tmp[wid] = inc;
    __syncthreads();
    if (wid == 0) {
        int w = (lane < 16) ? tmp[lane] : 0;
        int incw = w;
#pragma unroll
        for (int off = 1; off < 16; off <<= 1) {
            int u = __shfl_up(incw, off);
            if (lane >= off) incw += u;
        }
        if (lane < 16) tmp[lane] = incw - w;  // exclusive wave bases
    }
    __syncthreads();
    int base = tmp[wid] + (inc - s);
    arr[i0] = base;
    arr[i1] = base + v0;
    if (tid == 1023) *totalOut = base + v0 + v1;
    __syncthreads();
}

__global__ __launch_bounds__(1024) void k_all(
    const float* __restrict__ probas, const float* __restrict__ clusters,
    const int* __restrict__ edges, const int* __restrict__ keypts,
    Cand* __restrict__ spill, int pmax, float* __restrict__ out) {

    extern __shared__ char smem[];
    float4*   s_cluA = (float4*)(smem + OFF_CLUA);
    float4*   s_cluB = (float4*)(smem + OFF_CLUB);
    float*    s_prob = (float*)(smem + OFF_CLUA);   // alias: valid after phase C
    int*      s_pk   = (int*)(smem + OFF_PK);
    int*      s_q    = (int*)(smem + OFF_Q);
    int*      s_cur  = (int*)(smem + OFF_CUR);
    uint16_t* s_csr  = (uint16_t*)(smem + OFF_CSR);
    float*    s_bc   = (float*)(smem + OFF_BC);
    uint8_t*  s_clst = (uint8_t*)(smem + OFF_CLST);
    uint16_t* s_pa   = (uint16_t*)(smem + OFF_PA);
    int*      s_tmp  = (int*)(smem + OFF_TMP);
    int*      s_hist = (int*)(smem + OFF_HIST);
    float*    s_wsum = (float*)(smem + OFF_WSUM);
    int*      s_wcnt = (int*)(smem + OFF_WCNT);
    int*      s_misc = (int*)(smem + OFF_MISC);

    int tid = threadIdx.x;

    // preload edges + probas into regs (overlaps cluster-staging latency)
    const int2* ed2 = (const int2*)edges;
    int2 pre[8];
#pragma unroll
    for (int it = 0; it < 8; ++it) pre[it] = ed2[tid + it * NTHR];
    const float4* p4 = (const float4*)probas;
    float4 pp0 = p4[tid], pp1 = p4[tid + 1024];

    s_pk[tid] = 0; s_pk[tid + 1024] = 0;
    if (tid == 0) s_misc[0] = 0;

    // ===== A1: stage clusters coalesced into LDS + per-node argmax =====
    const float4* c4 = (const float4*)clusters;
#pragma unroll
    for (int r = 0; r < 2; ++r) {
        int n = tid + r * 1024;
        float4 a = c4[2 * n], b = c4[2 * n + 1];
        s_cluA[n] = a; s_cluB[n] = b;
        s_clst[n] = (uint8_t)argmax8(a, b);
    }
    __syncthreads();
    if (tid < L_CONST)
        atomicOr((uint32_t*)&s_misc[0], 1u << s_clst[keypts[tid]]);
    __syncthreads();
    uint32_t m = (uint32_t)s_misc[0];

    // ===== A2: per-edge flag + packed counts + precomputed bc (clusters in LDS) =====
    uint32_t af[8];  // anchor(<<2) | flag
#pragma unroll
    for (int it = 0; it < 8; ++it) {
        int e = tid + it * NTHR;
        int2 p = pre[it];
        int c0 = s_clst[p.x], c1 = s_clst[p.y];
        int f = 0;
        if ((((m >> c0) | (m >> c1)) & 1u)) f = (c0 == c1) ? 1 : 2;  // 1=pos, 2=neg
        af[it] = ((uint32_t)p.x << 2) | (uint32_t)f;
        if (f == 1)      atomicAdd(&s_pk[p.x], 1);
        else if (f == 2) atomicAdd(&s_pk[p.x], 0x10000);
        float4 a0 = s_cluA[p.x], a1 = s_cluB[p.x];
        float4 b0 = s_cluA[p.y], b1 = s_cluB[p.y];
        float s = __builtin_amdgcn_sqrtf(a0.x * b0.x);  // k ascending, matches ref order
        s += __builtin_amdgcn_sqrtf(a0.y * b0.y);
        s += __builtin_amdgcn_sqrtf(a0.z * b0.z);
        s += __builtin_amdgcn_sqrtf(a0.w * b0.w);
        s += __builtin_amdgcn_sqrtf(a1.x * b1.x);
        s += __builtin_amdgcn_sqrtf(a1.y * b1.y);
        s += __builtin_amdgcn_sqrtf(a1.z * b1.z);
        s += __builtin_amdgcn_sqrtf(a1.w * b1.w);
        s_bc[e] = s;
    }
    __syncthreads();

    // ===== B: pair counts + in-place scans =====
    {
        int i0 = 2 * tid, i1 = i0 + 1;
        int p0 = s_pk[i0], p1 = s_pk[i1];
        s_q[i0] = (p0 & 0xFFFF) * (p0 >> 16);
        s_q[i1] = (p1 & 0xFFFF) * (p1 >> 16);
    }
    __syncthreads();
    scan_inplace(s_pk, s_tmp, &s_misc[1]);
    scan_inplace(s_q, s_tmp, &s_misc[2]);
    s_cur[2 * tid] = s_pk[2 * tid];
    s_cur[2 * tid + 1] = s_pk[2 * tid + 1];
    __syncthreads();
    int nPosTot = s_misc[1] & 0xFFFF;
    int nNegTot = s_misc[1] >> 16;
    int totQ = s_misc[2];
    int P = totQ; if (P > pmax) P = pmax;

    // ===== C: CSR fill + pairAnchor table + probas->LDS (s_cluA dead after A2) =====
#pragma unroll
    for (int it = 0; it < 8; ++it) {
        int f = (int)(af[it] & 3u);
        int a = (int)(af[it] >> 2);
        int e = tid + it * NTHR;
        if (f == 1) {
            int old = atomicAdd(&s_cur[a], 1);
            s_csr[old & 0xFFFF] = (uint16_t)e;
        } else if (f == 2) {
            int old = atomicAdd(&s_cur[a], 0x10000);
            s_csr[nPosTot + (old >> 16)] = (uint16_t)e;
        }
    }
    for (int a = tid; a < N_CONST; a += NTHR) {
        int q0 = s_q[a];
        int q1 = (a < N_CONST - 1) ? s_q[a + 1] : totQ;
        for (int t = q0; t < q1 && t < TCAP; ++t) s_pa[t] = (uint16_t)a;
    }
    ((float4*)s_prob)[tid] = pp0;          // overwrite dead cluster region
    ((float4*)s_prob)[tid + 1024] = pp1;
    __syncthreads();

    // ===== D: one thread per valid pair; anchor via table; bc via 2 scalar reads =====
    auto make_cand = [&](int t, float& val, uint32_t& pack) {
        int a;
        if (t < TCAP) a = (int)s_pa[t];
        else {  // fallback (statistically unused)
            int lo = 0, hi = N_CONST - 1;
#pragma unroll
            for (int itr = 0; itr < 11; ++itr) {
                int mid = (lo + hi + 1) >> 1;
                if (s_q[mid] <= t) lo = mid; else hi = mid - 1;
            }
            a = lo;
        }
        int loc = t - s_q[a];
        int pk = s_pk[a];
        int pb = pk & 0xFFFF, nb = pk >> 16;
        int nextN = (a < N_CONST - 1) ? (s_pk[a + 1] >> 16) : nNegTot;
        int nn = nextN - nb;  // >= 1 for any anchor owning pairs
        int ip = loc / nn;
        int jn = loc - ip * nn;
        int i = s_csr[pb + ip];
        int j = s_csr[nPosTot + nb + jn];
        float w = 1.0f - 0.5f * (s_bc[i] + s_bc[j]);
        val = (w > 0.0f)
            ? __logf(fmaxf(w, EPS_F)) + gumbel_at((uint32_t)i * E_CONST + (uint32_t)j)
            : -INFINITY;  // ref: logw=-inf -> excluded via ok mask
        pack = ((uint32_t)i << 16) | (uint32_t)j;
    };

    float vval0 = 0.f, vval1 = 0.f, vval2 = 0.f, vval3 = 0.f;  // static-indexed (rule #20)
    uint32_t vpk0 = 0, vpk1 = 0, vpk2 = 0, vpk3 = 0;
    if (tid        < P) make_cand(tid,        vval0, vpk0);
    if (tid + 1024 < P) make_cand(tid + 1024, vval1, vpk1);
    if (tid + 2048 < P) make_cand(tid + 2048, vval2, vpk2);
    if (tid + 3072 < P) make_cand(tid + 3072, vval3, vpk3);
    for (int t = tid + RCAP; t < P; t += NTHR) {  // spill path (statistically unused)
        float v; uint32_t pk;
        make_cand(t, v, pk);
        spill[t - RCAP].val = v; spill[t - RCAP].pack = pk;
    }
    uint32_t vk0 = sortable_key(vval0), vk1 = sortable_key(vval1);
    uint32_t vk2 = sortable_key(vval2), vk3 = sortable_key(vval3);
    __syncthreads();

    // ===== E: 4-pass radix threshold (256-bin LDS-atomic hist; wave-0 suffix scan) =====
    uint32_t* s_prefix = (uint32_t*)&s_misc[3];
    int*      s_target = &s_misc[4];
    int M = P;
    uint32_t thr = 0;
    if (M > MAXS) {
        if (tid == 0) { *s_prefix = 0; *s_target = MAXS; }
        __syncthreads();
        for (int pass = 0; pass < 4; ++pass) {
            int shift = 24 - 8 * pass;
            if (tid < 256) s_hist[tid] = 0;
            __syncthreads();
            uint32_t pfx = *s_prefix;
            if (tid        < M && (pass == 0 || (vk0 >> (shift + 8)) == pfx)) atomicAdd(&s_hist[(vk0 >> shift) & 255], 1);
            if (tid + 1024 < M && (pass == 0 || (vk1 >> (shift + 8)) == pfx)) atomicAdd(&s_hist[(vk1 >> shift) & 255], 1);
            if (tid + 2048 < M && (pass == 0 || (vk2 >> (shift + 8)) == pfx)) atomicAdd(&s_hist[(vk2 >> shift) & 255], 1);
            if (tid + 3072 < M && (pass == 0 || (vk3 >> (shift + 8)) == pfx)) atomicAdd(&s_hist[(vk3 >> shift) & 255], 1);
            for (int t = tid + RCAP; t < M; t += NTHR) {
                uint32_t k = sortable_key(spill[t - RCAP].val);
                if (pass == 0 || (k >> (shift + 8)) == pfx)
                    atomicAdd(&s_hist[(k >> shift) & 255], 1);
            }
            __syncthreads();
            if (tid < 64) {  // wave 0: lane L owns bins 4L..4L+3, suffix-scan select
                int h0 = s_hist[4 * tid], h1 = s_hist[4 * tid + 1];
                int h2 = s_hist[4 * tid + 2], h3 = s_hist[4 * tid + 3];
                int sincl = h0 + h1 + h2 + h3;
#pragma unroll
                for (int off = 1; off < 64; off <<= 1) {
                    int v = __shfl_down(sincl, off);
                    if (tid + off < 64) sincl += v;
                }
                int excl = __shfl_down(sincl, 1);
                if (tid == 63) excl = 0;
                int suf3 = excl + h3;
                int suf2 = suf3 + h2;
                int suf1 = suf2 + h1;
                int suf0 = suf1 + h0;
                int tgt = *s_target;
                uint32_t pfxOld = *s_prefix;
                if      (suf0 >= tgt && suf1 < tgt) { *s_prefix = (pfxOld << 8) | (4u*tid+0); *s_target = tgt - suf1; }
                else if (suf1 >= tgt && suf2 < tgt) { *s_prefix = (pfxOld << 8) | (4u*tid+1); *s_target = tgt - suf2; }
                else if (suf2 >= tgt && suf3 < tgt) { *s_prefix = (pfxOld << 8) | (4u*tid+2); *s_target = tgt - suf3; }
                else if (suf3 >= tgt && excl < tgt) { *s_prefix = (pfxOld << 8) | (4u*tid+3); *s_target = tgt - excl; }
            }
            __syncthreads();
        }
        thr = *s_prefix;  // exact sortable key of the 400th-largest value
    }

    // ===== F: deterministic reduce of selected terms (probas from LDS) =====
    float mysum = 0.f;
    int myc = 0;
    auto accum = [&](int t, float v, uint32_t k, uint32_t pk) {
        if (t < M && v != -INFINITY && k >= thr) {
            int i = (int)(pk >> 16), j = (int)(pk & 0xFFFFu);
            float pi = s_prob[i], pj = s_prob[j];
            mysum += __logf(pi / (pi + pj));  // ~1e-6 abs err, threshold 1.7e-2
            myc++;
        }
    };
    accum(tid,        vval0, vk0, vpk0);
    accum(tid + 1024, vval1, vk1, vpk1);
    accum(tid + 2048, vval2, vk2, vpk2);
    accum(tid + 3072, vval3, vk3, vpk3);
    for (int t = tid + RCAP; t < M; t += NTHR) {
        Cand c = spill[t - RCAP];
        accum(t, c.val, sortable_key(c.val), c.pack);
    }
#pragma unroll
    for (int off = 32; off > 0; off >>= 1) {
        mysum += __shfl_down(mysum, off);
        myc   += __shfl_down(myc, off);
    }
    int wid = tid >> 6;
    if ((tid & 63) == 0) { s_wsum[wid] = mysum; s_wcnt[wid] = myc; }
    __syncthreads();
    if (tid == 0) {
        float s = 0.f; int c = 0;
        for (int w = 0; w < 16; ++w) { s += s_wsum[w]; c += s_wcnt[w]; }
        if (c < 1) c = 1;
        out[0] = -s / (float)c;
    }
}

extern "C" void kernel_launch(void* const* d_in, const int* in_sizes, int n_in,
                              void* d_out, int out_size, void* d_ws, size_t ws_size,
                              hipStream_t stream) {
    const float* probas   = (const float*)d_in[0];
    const float* clusters = (const float*)d_in[1];
    const int*   edges    = (const int*)d_in[2];
    const int*   keypts   = (const int*)d_in[3];
    float* out = (float*)d_out;

    Cand* spill = (Cand*)d_ws;
    int spill_cap = (int)(ws_size / sizeof(Cand));
    if (spill_cap > 61440) spill_cap = 61440;
    int pmax = RCAP + spill_cap;

    // allow >64KB dynamic LDS (idempotent host-side call; not a stream op)
    hipFuncSetAttribute((const void*)k_all,
                        hipFuncAttributeMaxDynamicSharedMemorySize, LDS_BYTES);

    k_all<<<1, NTHR, LDS_BYTES, stream>>>(probas, clusters, edges, keypts,
                                          spill, pmax, out);
}